// Round 12
// baseline (8756.484 us; speedup 1.0000x reference)
//
#include <hip/hip_runtime.h>
#include <math.h>

#define NOPS 7
#define KITERS 3
#define NBLK 31     // 31 perm-blocks x 4 masks = 124 rounds = up to 4 full sweeps
#define WPB 4       // waves (=matrices) per block; no cross-wave sharing
#define CHKFROM 0   // full-convergence check every block (exit saves perm4s)
#define CONVEPS 3e-5f
#define SKIPEPS 3e-5f   // per-round skip: mask-round with all |apq|<=tau is identity

// Single-wave LDS discipline: DS ops from one wave are processed IN ORDER, so a
// ds_read after a ds_write to the same address needs NO s_waitcnt. We only need a
// compiler fence to preserve program order; HW waits for data-use are auto-inserted.
#define WFENCE() asm volatile("" ::: "memory")
// Global park/un-park round-trip still needs a VMEM drain (no ordering guarantee).
#define VSYNC() asm volatile("s_waitcnt vmcnt(0)" ::: "memory")

// lane-xor exchange: M=1,2 via DPP quad_perm, M=4,8 via ds_swizzle (32-lane groups)
template<int M> __device__ __forceinline__ float xshuf(float x);
template<> __device__ __forceinline__ float xshuf<1>(float x) {
    return __int_as_float(__builtin_amdgcn_mov_dpp(__float_as_int(x), 0xB1, 0xF, 0xF, true));
}
template<> __device__ __forceinline__ float xshuf<2>(float x) {
    return __int_as_float(__builtin_amdgcn_mov_dpp(__float_as_int(x), 0x4E, 0xF, 0xF, true));
}
template<> __device__ __forceinline__ float xshuf<4>(float x) {
    return __int_as_float(__builtin_amdgcn_ds_swizzle(__float_as_int(x), (4 << 10) | 0x1F));
}
template<> __device__ __forceinline__ float xshuf<8>(float x) {
    return __int_as_float(__builtin_amdgcn_ds_swizzle(__float_as_int(x), (8 << 10) | 0x1F));
}

// One Jacobi round, pairing {x, x^M}  (r9-verified; fast-math angle -- Jacobi
// self-corrects ~ulp angle error).  Lane (il, c=lane>>5) holds:
//   a[j] = M[il][il^(16c+j)] (xor-aligned), v[j] = V[il][16c+j].
// Adaptive skip: if every |a[M]| (the mask's off-diagonals, held by chunk-0 lanes)
// is <= SKIPEPS, all 16 rotations are ~identity -> skip the round entirely.
// Exactly semantics-preserving: labels advance via perm4 regardless.
template<int M>
__device__ __forceinline__ void jround(float (&a)[16], float (&v)[16], float2* ct,
                                       const int il, const int wlane, const int fKb) {
    const float apq = a[M];
    const float amx = (wlane & 32) ? 0.f : fabsf(apq);
    if (!__any(amx > SKIPEPS)) return;
    const int fil = (il & (M - 1)) | ((il >> 1) & ~(M - 1));   // 4-bit pair id of row il
    const float dq  = xshuf<M>(a[0]);    // partner diagonal (valid on chunk-0 lanes)
    float th = (dq - a[0]) * __builtin_amdgcn_rcpf(apq + apq);
    float t  = copysignf(__builtin_amdgcn_rcpf(
                   fabsf(th) + __builtin_amdgcn_sqrtf(fmaf(th, th, 1.f))), th);
    float cc = __builtin_amdgcn_rsqf(fmaf(t, t, 1.f));
    float ss = t * cc;
    if (!(fabsf(apq) > 1e-12f)) { cc = 1.f; ss = 0.f; }   // also guards NaN path
    if ((wlane & (32 | M)) == 0) ct[fil] = make_float2(cc, ss);   // chunk0 p-role lanes
    WFENCE();   // in-order DS: reads below see the write, no drain needed
    const float2 me = ct[fil];
    const float sg = (il & M) ? 1.f : -1.f;
    const float c0 = me.x, s0 = sg * me.y;
    const int fb = fil ^ fKb;                         // hoisted cs index base
    const float4* cup = (const float4*)(ct + fKb);    // cu half-table, uniform-per-chunk
    // column rotations on a (pairs (j,j^M) = cols (il^K, il^K^M)) and on v (slot pair)
    float4 q;
    #pragma unroll
    for (int j = 0; j < 16; ++j) {
        if (j & M) continue;
        const int fj = (j & (M - 1)) | ((j >> 1) & ~(M - 1));   // ascends 0..7
        const float2 cs = ct[fb ^ fj];                // per-lane gather (b64)
        const float sl = sg * cs.y;
        const float ak = a[j], am = a[j ^ M];
        a[j]     = fmaf( sl, am, cs.x * ak);
        a[j ^ M] = fmaf(-sl, ak, cs.x * am);
        if ((fj & 1) == 0) q = cup[fj >> 1];          // uniform b128: entries fj, fj+1
        const float cux = (fj & 1) ? q.z : q.x;
        const float cuy = (fj & 1) ? q.w : q.y;
        const float vk = v[j], vm = v[j ^ M];
        v[j]     = fmaf(-cuy, vm, cux * vk);
        v[j ^ M] = fmaf( cuy, vk, cux * vm);
    }
    // row mix: own' = c0*own + s0*partner (reads partner's post-colrot regs)
    #pragma unroll
    for (int j = 0; j < 16; ++j) {
        if (j & M) continue;
        const float r1 = xshuf<M>(a[j ^ M]);
        const float r2 = xshuf<M>(a[j]);
        a[j]     = fmaf(s0, r1, c0 * a[j]);
        a[j ^ M] = fmaf(s0, r2, c0 * a[j ^ M]);
    }
}

__global__ __launch_bounds__(64 * WPB)
void karcher_kernel(const float* __restrict__ spds, const float* __restrict__ alphas,
                    float* __restrict__ out, int Mtot) {
    __shared__ __align__(16) float XIb[WPB][1024];   // per-wave: Xih (then E / T2)
    __shared__ __align__(16) float SCb[WPB][1024];   // per-wave scratch stage
    __shared__ __align__(64) float2 CTb[WPB][16];    // per-wave angle table
    __shared__ float FDAb[WPB][32];
    __shared__ float FDBb[WPB][32];
    __shared__ float WSb[WPB][8];

    const int tid   = threadIdx.x;
    const int wid   = tid >> 6;
    const int wlane = tid & 63;
    const int il    = wlane & 31;       // row
    const int cbit  = wlane >> 5;       // column chunk
    const int cbase = cbit << 4;
    const int fKb   = cbit << 3;
    const int c13   = cbit ? 13 : 0;    // L4(16) = 13
    const int mat   = blockIdx.x * WPB + wid;
    const bool rr   = (il < 30);

    float* XI  = XIb[wid];
    float* SC  = SCb[wid];
    float2* CT = CTb[wid];
    float* FDA = FDAb[wid];
    float* FDB = FDBb[wid];
    float* WS  = WSb[wid];

    if (mat >= Mtot) return;   // whole-wave uniform; no block-wide barriers exist

    if (wlane == 0) {
        float aa[NOPS], mx = -1e30f, sum = 0.f;
        #pragma unroll
        for (int o = 0; o < NOPS; ++o) { aa[o] = alphas[o]; mx = fmaxf(mx, aa[o]); }
        #pragma unroll
        for (int o = 0; o < NOPS; ++o) { aa[o] = expf(aa[o] - mx); sum += aa[o]; }
        #pragma unroll
        for (int o = 0; o < NOPS; ++o) WS[o] = aa[o] / sum;
    }

    int l4row = il;   // L^4 of own row (companion matrix of x^5+x^2+1)
    #pragma unroll
    for (int i = 0; i < 4; ++i) l4row = ((l4row << 1) & 31) ^ ((l4row & 16) ? 5 : 0);

    const size_t ostr = (size_t)Mtot * 900;
    const float* Abase = spds + (size_t)mat * 900 + (size_t)il * 30 + cbase;
    float* orow = out + (size_t)mat * 900 + (size_t)il * 30 + cbase;   // park + final out

    auto stage16 = [&](float* buf, const float (&r)[16]) {   // buf[t*32+il], CF banks
        #pragma unroll
        for (int j = 0; j < 16; ++j) buf[((cbase + j) << 5) + il] = r[j];
    };
    auto xload16 = [&](const float* buf, float (&a)[16]) {   // a[j] = M[il][il^(16c+j)]
        #pragma unroll
        for (int j = 0; j < 16; ++j) a[j] = buf[((il ^ (cbase + j)) << 5) + il];
    };
    auto perm4 = [&](float (&a)[16], float (&v)[16]) {       // relabel slots by L^4
        constexpr int L4T[16] = {0,16,5,21,10,26,15,31,20,4,17,1,30,14,27,11};
        // xor-aligned stage: SC[t*32+r] = M[r][r^t]; in-order DS -> no drains at all
        #pragma unroll
        for (int j = 0; j < 16; ++j) SC[((cbase + j) << 5) + il] = a[j];
        WFENCE();
        #pragma unroll
        for (int j = 0; j < 16; ++j) a[j] = SC[((L4T[j] ^ c13) << 5) + l4row];
        WFENCE();
        #pragma unroll
        for (int j = 0; j < 16; ++j) SC[((cbase + j) << 5) + il] = v[j];
        WFENCE();
        #pragma unroll
        for (int j = 0; j < 16; ++j) v[j] = SC[((L4T[j] ^ c13) << 5) + il];
        WFENCE();
    };
    auto jacobi = [&](float (&a)[16], float (&v)[16]) {
        #pragma unroll
        for (int j = 0; j < 16; ++j) v[j] = (cbase + j == il) ? 1.f : 0.f;
        #pragma unroll 1
        for (int b = 0; b < NBLK; ++b) {
            jround<1>(a, v, CT, il, wlane, fKb);
            jround<2>(a, v, CT, il, wlane, fKb);
            jround<4>(a, v, CT, il, wlane, fKb);
            jround<8>(a, v, CT, il, wlane, fKb);
            if (b >= CHKFROM) {   // early exit OK: slot labels may end permuted, but
                                  // all eigen-consumers sum over ALL 32 slots (k<32)
                float mx = cbit ? fabsf(a[0]) : 0.f;
                #pragma unroll
                for (int j = 1; j < 16; ++j) mx = fmaxf(mx, fabsf(a[j]));
                if (!__any(mx > CONVEPS)) break;
            }
            if (b != NBLK - 1) perm4(a, v);
        }
    };
    auto loadA = [&](const float* Ao, float (&r)[16]) {      // own 16-col slice of a row
        #pragma unroll
        for (int u = 0; u < 7; ++u) {
            const float2 p = *(const float2*)(Ao + 2 * u);
            r[2 * u] = p.x; r[2 * u + 1] = p.y;
        }
        if (cbit == 0) {
            const float2 p = *(const float2*)(Ao + 14);
            r[14] = p.x; r[15] = p.y;
        }
    };
    auto fma16 = [&](const float* buf, const int k, const float c, float (&acc)[16]) {
        const float4* bp = (const float4*)(buf + (k << 5) + cbase);
        #pragma unroll
        for (int q = 0; q < 4; ++q) {
            const float4 b = bp[q];
            acc[4*q+0] = fmaf(c, b.x, acc[4*q+0]);
            acc[4*q+1] = fmaf(c, b.y, acc[4*q+1]);
            acc[4*q+2] = fmaf(c, b.z, acc[4*q+2]);
            acc[4*q+3] = fmaf(c, b.w, acc[4*q+3]);
        }
    };

    WFENCE();   // WS visible (in-order DS within wave)

    // ---- X = sum_o w_o A_o (padding rows/cols stay exactly 0) ----
    float X[16];
    #pragma unroll
    for (int j = 0; j < 16; ++j) X[j] = 0.f;
    if (rr) {
        #pragma unroll 1
        for (int o = 0; o < NOPS; ++o) {
            const float wo = WS[o];
            float r[16];
            #pragma unroll
            for (int j = 0; j < 16; ++j) r[j] = 0.f;
            loadA(Abase + (size_t)o * ostr, r);
            #pragma unroll
            for (int j = 0; j < 16; ++j) X[j] = fmaf(wo, r[j], X[j]);
        }
    }

    float Lacc[16];

    #pragma unroll 1
    for (int it = 0; it < KITERS; ++it) {
        // ---- eigh(X) ----
        WFENCE();
        stage16(SC, X);
        WFENCE();
        float a1[16], v1[16];
        xload16(SC, a1);
        jacobi(a1, v1);
        if (wlane < 32) {
            const float lam = fmaxf(a1[0], 1e-8f);
            const float sq = sqrtf(lam);
            FDA[il] = sq;
            FDB[il] = 1.f / sq;
        }
        WFENCE();
        stage16(SC, v1);
        WFENCE();
        // ---- Xh -> park in out[], Xih -> XI ----
        // k<32: permutation-invariant; pad eigenvectors are exactly e30/e31, so
        // clamped pad eigenvalues contribute 0 to all real rows/cols.
        {
            float xh[16], xi[16];
            #pragma unroll
            for (int j = 0; j < 16; ++j) { xh[j] = 0.f; xi[j] = 0.f; }
            #pragma unroll 2
            for (int k = 0; k < 32; ++k) {
                const float vk = SC[(k << 5) + il];   // V[il][k]
                const float c1 = FDA[k] * vk;
                const float c2 = FDB[k] * vk;
                const float4* bp = (const float4*)(SC + (k << 5) + cbase);   // V[t][k]
                #pragma unroll
                for (int q = 0; q < 4; ++q) {
                    const float4 b = bp[q];
                    xh[4*q+0] = fmaf(c1, b.x, xh[4*q+0]); xi[4*q+0] = fmaf(c2, b.x, xi[4*q+0]);
                    xh[4*q+1] = fmaf(c1, b.y, xh[4*q+1]); xi[4*q+1] = fmaf(c2, b.y, xi[4*q+1]);
                    xh[4*q+2] = fmaf(c1, b.z, xh[4*q+2]); xi[4*q+2] = fmaf(c2, b.z, xi[4*q+2]);
                    xh[4*q+3] = fmaf(c1, b.w, xh[4*q+3]); xi[4*q+3] = fmaf(c2, b.w, xi[4*q+3]);
                }
            }
            if (rr) {   // park Xh row (each lane round-trips only its own slice)
                #pragma unroll
                for (int u = 0; u < 7; ++u)
                    *(float2*)(orow + 2 * u) = make_float2(xh[2*u], xh[2*u+1]);
                if (cbit == 0)
                    *(float2*)(orow + 14) = make_float2(xh[14], xh[15]);
            }
            WFENCE();
            stage16(XI, xi);
        }
        #pragma unroll
        for (int j = 0; j < 16; ++j) Lacc[j] = 0.f;

        // ---- op loop: Lacc += w_o logm(Xih A_o Xih) ----
        #pragma unroll 1
        for (int o = 0; o < NOPS; ++o) {
            float ar[16];
            #pragma unroll
            for (int j = 0; j < 16; ++j) ar[j] = 0.f;
            if (rr) loadA(Abase + (size_t)o * ostr, ar);
            WFENCE();
            stage16(SC, ar);
            WFENCE();
            float T[16];
            #pragma unroll
            for (int j = 0; j < 16; ++j) T[j] = 0.f;
            #pragma unroll 2
            for (int k = 0; k < 30; ++k)          // T = Xih * A (orig coords)
                fma16(SC, k, XI[(k << 5) + il], T);
            WFENCE();
            stage16(SC, T);                        // A dead (in-order WAR safe)
            WFENCE();
            float md[16];
            #pragma unroll
            for (int j = 0; j < 16; ++j) md[j] = 0.f;
            #pragma unroll 2
            for (int k = 0; k < 30; ++k)          // mid = T * Xih (orig coords)
                fma16(XI, k, SC[(k << 5) + il], md);
            WFENCE();
            stage16(SC, md);
            WFENCE();
            float a2[16], v2[16];
            xload16(SC, a2);
            jacobi(a2, v2);
            if (wlane < 32) FDA[il] = logf(fmaxf(a2[0], 1e-8f));
            WFENCE();
            stage16(SC, v2);
            WFENCE();
            const float wo = WS[o];
            #pragma unroll 2
            for (int k = 0; k < 32; ++k)          // Lacc += wo * V log(L) V^T (all slots)
                fma16(SC, k, wo * FDA[k] * SC[(k << 5) + il], Lacc);
        }

        // ---- E = expm(L); X' = Xh E Xh ----
        WFENCE();
        stage16(SC, Lacc);
        WFENCE();
        float a3[16], v3[16];
        xload16(SC, a3);
        jacobi(a3, v3);
        if (wlane < 32) FDA[il] = expf(fmaxf(a3[0], 1e-8f));   // ref clamps before exp
        WFENCE();
        stage16(SC, v3);
        WFENCE();
        float E[16];
        #pragma unroll
        for (int j = 0; j < 16; ++j) E[j] = 0.f;
        #pragma unroll 2
        for (int k = 0; k < 32; ++k)              // E = V exp(L) V^T (all slots)
            fma16(SC, k, FDA[k] * SC[(k << 5) + il], E);
        // un-park Xh row slice (order the global store->load round-trip)
        float xr[16];
        #pragma unroll
        for (int j = 0; j < 16; ++j) xr[j] = 0.f;
        VSYNC();
        if (rr) loadA(orow, xr);
        WFENCE();
        stage16(XI, E);        // XI = E (Xih dead)
        stage16(SC, xr);       // SC = Xh (v3 dead; in-order safe)
        WFENCE();
        float T2[16];
        #pragma unroll
        for (int j = 0; j < 16; ++j) T2[j] = 0.f;
        #pragma unroll 2
        for (int k = 0; k < 30; ++k)              // T2 = Xh * E (orig coords)
            fma16(XI, k, SC[(k << 5) + il], T2);
        WFENCE();
        stage16(XI, T2);       // E dead
        WFENCE();
        #pragma unroll
        for (int j = 0; j < 16; ++j) X[j] = 0.f;
        #pragma unroll 2
        for (int k = 0; k < 30; ++k)              // X' = T2 * Xh (orig coords)
            fma16(SC, k, XI[(k << 5) + il], X);
    }

    if (rr) {
        #pragma unroll
        for (int u = 0; u < 7; ++u)
            *(float2*)(orow + 2 * u) = make_float2(X[2*u], X[2*u+1]);
        if (cbit == 0)
            *(float2*)(orow + 14) = make_float2(X[14], X[15]);
    }
}

extern "C" void kernel_launch(void* const* d_in, const int* in_sizes, int n_in,
                              void* d_out, int out_size, void* d_ws, size_t ws_size,
                              hipStream_t stream) {
    const float* spds   = (const float*)d_in[0];
    const float* alphas = (const float*)d_in[1];
    float* out = (float*)d_out;
    const int Mtot = in_sizes[0] / (NOPS * 900);   // 8192
    karcher_kernel<<<dim3((Mtot + WPB - 1) / WPB), dim3(64 * WPB), 0, stream>>>(
        spds, alphas, out, Mtot);
}

// Round 13
// 7843.269 us; speedup vs baseline: 1.1164x; 1.1164x over previous
//
#include <hip/hip_runtime.h>
#include <math.h>

#define NOPS 7
#define KITERS 3
#define NBLK 31     // 31 perm-blocks x 4 masks = 124 rounds = up to 4 full sweeps
#define WPB 4       // waves (=matrices) per block; no cross-wave sharing
#define CHKFROM 6   // start convergence checks after this block
#define CONVEPS 1e-5f

// Single-wave LDS discipline: DS ops from one wave are processed IN ORDER, so a
// ds_read after a ds_write to the same address needs NO s_waitcnt. We only need a
// compiler fence to preserve program order; HW waits for data-use are auto-inserted.
#define WFENCE() asm volatile("" ::: "memory")
// Global park/un-park round-trip still needs a VMEM drain (no ordering guarantee).
#define VSYNC() asm volatile("s_waitcnt vmcnt(0)" ::: "memory")

// lane-xor exchange: M=1,2 via DPP quad_perm, M=4,8 via ds_swizzle (32-lane groups)
template<int M> __device__ __forceinline__ float xshuf(float x);
template<> __device__ __forceinline__ float xshuf<1>(float x) {
    return __int_as_float(__builtin_amdgcn_mov_dpp(__float_as_int(x), 0xB1, 0xF, 0xF, true));
}
template<> __device__ __forceinline__ float xshuf<2>(float x) {
    return __int_as_float(__builtin_amdgcn_mov_dpp(__float_as_int(x), 0x4E, 0xF, 0xF, true));
}
template<> __device__ __forceinline__ float xshuf<4>(float x) {
    return __int_as_float(__builtin_amdgcn_ds_swizzle(__float_as_int(x), (4 << 10) | 0x1F));
}
template<> __device__ __forceinline__ float xshuf<8>(float x) {
    return __int_as_float(__builtin_amdgcn_ds_swizzle(__float_as_int(x), (8 << 10) | 0x1F));
}

// One Jacobi round, pairing {x, x^M}  (r9-verified; fast-math angle -- Jacobi
// self-corrects ~ulp angle error).  Lane (il, c=lane>>5) holds:
//   a[j] = M[il][il^(16c+j)] (xor-aligned), v[j] = V[il][16c+j].
template<int M>
__device__ __forceinline__ void jround(float (&a)[16], float (&v)[16], float2* ct,
                                       const int il, const int wlane, const int fKb) {
    const int fil = (il & (M - 1)) | ((il >> 1) & ~(M - 1));   // 4-bit pair id of row il
    const float dq  = xshuf<M>(a[0]);    // partner diagonal (valid on chunk-0 lanes)
    const float apq = a[M];
    float th = (dq - a[0]) * __builtin_amdgcn_rcpf(apq + apq);
    float t  = copysignf(__builtin_amdgcn_rcpf(
                   fabsf(th) + __builtin_amdgcn_sqrtf(fmaf(th, th, 1.f))), th);
    float cc = __builtin_amdgcn_rsqf(fmaf(t, t, 1.f));
    float ss = t * cc;
    if (!(fabsf(apq) > 1e-12f)) { cc = 1.f; ss = 0.f; }   // also guards NaN path
    if ((wlane & (32 | M)) == 0) ct[fil] = make_float2(cc, ss);   // chunk0 p-role lanes
    WFENCE();   // in-order DS: reads below see the write, no drain needed
    const float2 me = ct[fil];
    const float sg = (il & M) ? 1.f : -1.f;
    const float c0 = me.x, s0 = sg * me.y;
    const int fb = fil ^ fKb;                         // hoisted cs index base
    const float4* cup = (const float4*)(ct + fKb);    // cu half-table, uniform-per-chunk
    // column rotations on a (pairs (j,j^M) = cols (il^K, il^K^M)) and on v (slot pair)
    float4 q;
    #pragma unroll
    for (int j = 0; j < 16; ++j) {
        if (j & M) continue;
        const int fj = (j & (M - 1)) | ((j >> 1) & ~(M - 1));   // ascends 0..7
        const float2 cs = ct[fb ^ fj];                // per-lane gather (b64)
        const float sl = sg * cs.y;
        const float ak = a[j], am = a[j ^ M];
        a[j]     = fmaf( sl, am, cs.x * ak);
        a[j ^ M] = fmaf(-sl, ak, cs.x * am);
        if ((fj & 1) == 0) q = cup[fj >> 1];          // uniform b128: entries fj, fj+1
        const float cux = (fj & 1) ? q.z : q.x;
        const float cuy = (fj & 1) ? q.w : q.y;
        const float vk = v[j], vm = v[j ^ M];
        v[j]     = fmaf(-cuy, vm, cux * vk);
        v[j ^ M] = fmaf( cuy, vk, cux * vm);
    }
    // row mix: own' = c0*own + s0*partner (reads partner's post-colrot regs)
    #pragma unroll
    for (int j = 0; j < 16; ++j) {
        if (j & M) continue;
        const float r1 = xshuf<M>(a[j ^ M]);
        const float r2 = xshuf<M>(a[j]);
        a[j]     = fmaf(s0, r1, c0 * a[j]);
        a[j ^ M] = fmaf(s0, r2, c0 * a[j ^ M]);
    }
}

__global__ __launch_bounds__(64 * WPB)
void karcher_kernel(const float* __restrict__ spds, const float* __restrict__ alphas,
                    float* __restrict__ out, int Mtot) {
    __shared__ __align__(16) float XIb[WPB][1024];   // per-wave: Xih (then E / T2)
    __shared__ __align__(16) float SCb[WPB][1024];   // per-wave scratch stage
    __shared__ __align__(64) float2 CTb[WPB][16];    // per-wave angle table
    __shared__ float FDAb[WPB][32];
    __shared__ float FDBb[WPB][32];
    __shared__ float WSb[WPB][8];

    const int tid   = threadIdx.x;
    const int wid   = tid >> 6;
    const int wlane = tid & 63;
    const int il    = wlane & 31;       // row
    const int cbit  = wlane >> 5;       // column chunk
    const int cbase = cbit << 4;
    const int fKb   = cbit << 3;
    const int c13   = cbit ? 13 : 0;    // L4(16) = 13
    const int mat   = blockIdx.x * WPB + wid;
    const bool rr   = (il < 30);

    float* XI  = XIb[wid];
    float* SC  = SCb[wid];
    float2* CT = CTb[wid];
    float* FDA = FDAb[wid];
    float* FDB = FDBb[wid];
    float* WS  = WSb[wid];

    if (mat >= Mtot) return;   // whole-wave uniform; no block-wide barriers exist

    if (wlane == 0) {
        float aa[NOPS], mx = -1e30f, sum = 0.f;
        #pragma unroll
        for (int o = 0; o < NOPS; ++o) { aa[o] = alphas[o]; mx = fmaxf(mx, aa[o]); }
        #pragma unroll
        for (int o = 0; o < NOPS; ++o) { aa[o] = expf(aa[o] - mx); sum += aa[o]; }
        #pragma unroll
        for (int o = 0; o < NOPS; ++o) WS[o] = aa[o] / sum;
    }

    int l4row = il;   // L^4 of own row (companion matrix of x^5+x^2+1)
    #pragma unroll
    for (int i = 0; i < 4; ++i) l4row = ((l4row << 1) & 31) ^ ((l4row & 16) ? 5 : 0);

    const size_t ostr = (size_t)Mtot * 900;
    const float* Abase = spds + (size_t)mat * 900 + (size_t)il * 30 + cbase;
    float* orow = out + (size_t)mat * 900 + (size_t)il * 30 + cbase;   // park + final out

    auto stage16 = [&](float* buf, const float (&r)[16]) {   // buf[t*32+il], CF banks
        #pragma unroll
        for (int j = 0; j < 16; ++j) buf[((cbase + j) << 5) + il] = r[j];
    };
    auto xload16 = [&](const float* buf, float (&a)[16]) {   // a[j] = M[il][il^(16c+j)]
        #pragma unroll
        for (int j = 0; j < 16; ++j) a[j] = buf[((il ^ (cbase + j)) << 5) + il];
    };
    auto perm4 = [&](float (&a)[16], float (&v)[16]) {       // relabel slots by L^4
        constexpr int L4T[16] = {0,16,5,21,10,26,15,31,20,4,17,1,30,14,27,11};
        // xor-aligned stage: SC[t*32+r] = M[r][r^t]; in-order DS -> no drains at all
        #pragma unroll
        for (int j = 0; j < 16; ++j) SC[((cbase + j) << 5) + il] = a[j];
        WFENCE();
        #pragma unroll
        for (int j = 0; j < 16; ++j) a[j] = SC[((L4T[j] ^ c13) << 5) + l4row];
        WFENCE();
        #pragma unroll
        for (int j = 0; j < 16; ++j) SC[((cbase + j) << 5) + il] = v[j];
        WFENCE();
        #pragma unroll
        for (int j = 0; j < 16; ++j) v[j] = SC[((L4T[j] ^ c13) << 5) + il];
        WFENCE();
    };
    auto jacobi = [&](float (&a)[16], float (&v)[16]) {
        #pragma unroll
        for (int j = 0; j < 16; ++j) v[j] = (cbase + j == il) ? 1.f : 0.f;
        #pragma unroll 1
        for (int b = 0; b < NBLK; ++b) {
            jround<1>(a, v, CT, il, wlane, fKb);
            jround<2>(a, v, CT, il, wlane, fKb);
            jround<4>(a, v, CT, il, wlane, fKb);
            jround<8>(a, v, CT, il, wlane, fKb);
            if (b >= CHKFROM) {   // early exit OK: slot labels may end permuted, but
                                  // all eigen-consumers sum over ALL 32 slots (k<32)
                float mx = cbit ? fabsf(a[0]) : 0.f;
                #pragma unroll
                for (int j = 1; j < 16; ++j) mx = fmaxf(mx, fabsf(a[j]));
                if (!__any(mx > CONVEPS)) break;
            }
            if (b != NBLK - 1) perm4(a, v);
        }
    };
    auto loadA = [&](const float* Ao, float (&r)[16]) {      // own 16-col slice of a row
        #pragma unroll
        for (int u = 0; u < 7; ++u) {
            const float2 p = *(const float2*)(Ao + 2 * u);
            r[2 * u] = p.x; r[2 * u + 1] = p.y;
        }
        if (cbit == 0) {
            const float2 p = *(const float2*)(Ao + 14);
            r[14] = p.x; r[15] = p.y;
        }
    };
    auto fma16 = [&](const float* buf, const int k, const float c, float (&acc)[16]) {
        const float4* bp = (const float4*)(buf + (k << 5) + cbase);
        #pragma unroll
        for (int q = 0; q < 4; ++q) {
            const float4 b = bp[q];
            acc[4*q+0] = fmaf(c, b.x, acc[4*q+0]);
            acc[4*q+1] = fmaf(c, b.y, acc[4*q+1]);
            acc[4*q+2] = fmaf(c, b.z, acc[4*q+2]);
            acc[4*q+3] = fmaf(c, b.w, acc[4*q+3]);
        }
    };

    WFENCE();   // WS visible (in-order DS within wave)

    // ---- X = sum_o w_o A_o (padding rows/cols stay exactly 0) ----
    float X[16];
    #pragma unroll
    for (int j = 0; j < 16; ++j) X[j] = 0.f;
    if (rr) {
        #pragma unroll 1
        for (int o = 0; o < NOPS; ++o) {
            const float wo = WS[o];
            float r[16];
            #pragma unroll
            for (int j = 0; j < 16; ++j) r[j] = 0.f;
            loadA(Abase + (size_t)o * ostr, r);
            #pragma unroll
            for (int j = 0; j < 16; ++j) X[j] = fmaf(wo, r[j], X[j]);
        }
    }

    float Lacc[16];

    #pragma unroll 1
    for (int it = 0; it < KITERS; ++it) {
        // ---- eigh(X) ----
        WFENCE();
        stage16(SC, X);
        WFENCE();
        float a1[16], v1[16];
        xload16(SC, a1);
        jacobi(a1, v1);
        if (wlane < 32) {
            const float lam = fmaxf(a1[0], 1e-8f);
            const float sq = sqrtf(lam);
            FDA[il] = sq;
            FDB[il] = 1.f / sq;
        }
        WFENCE();
        stage16(SC, v1);
        WFENCE();
        // ---- Xh -> park in out[], Xih -> XI ----
        // k<32: permutation-invariant; pad eigenvectors are exactly e30/e31, so
        // clamped pad eigenvalues contribute 0 to all real rows/cols.
        {
            float xh[16], xi[16];
            #pragma unroll
            for (int j = 0; j < 16; ++j) { xh[j] = 0.f; xi[j] = 0.f; }
            #pragma unroll 2
            for (int k = 0; k < 32; ++k) {
                const float vk = SC[(k << 5) + il];   // V[il][k]
                const float c1 = FDA[k] * vk;
                const float c2 = FDB[k] * vk;
                const float4* bp = (const float4*)(SC + (k << 5) + cbase);   // V[t][k]
                #pragma unroll
                for (int q = 0; q < 4; ++q) {
                    const float4 b = bp[q];
                    xh[4*q+0] = fmaf(c1, b.x, xh[4*q+0]); xi[4*q+0] = fmaf(c2, b.x, xi[4*q+0]);
                    xh[4*q+1] = fmaf(c1, b.y, xh[4*q+1]); xi[4*q+1] = fmaf(c2, b.y, xi[4*q+1]);
                    xh[4*q+2] = fmaf(c1, b.z, xh[4*q+2]); xi[4*q+2] = fmaf(c2, b.z, xi[4*q+2]);
                    xh[4*q+3] = fmaf(c1, b.w, xh[4*q+3]); xi[4*q+3] = fmaf(c2, b.w, xi[4*q+3]);
                }
            }
            if (rr) {   // park Xh row (each lane round-trips only its own slice)
                #pragma unroll
                for (int u = 0; u < 7; ++u)
                    *(float2*)(orow + 2 * u) = make_float2(xh[2*u], xh[2*u+1]);
                if (cbit == 0)
                    *(float2*)(orow + 14) = make_float2(xh[14], xh[15]);
            }
            WFENCE();
            stage16(XI, xi);
        }
        #pragma unroll
        for (int j = 0; j < 16; ++j) Lacc[j] = 0.f;

        // ---- op loop: Lacc += w_o logm(Xih A_o Xih) ----
        #pragma unroll 1
        for (int o = 0; o < NOPS; ++o) {
            float ar[16];
            #pragma unroll
            for (int j = 0; j < 16; ++j) ar[j] = 0.f;
            if (rr) loadA(Abase + (size_t)o * ostr, ar);
            WFENCE();
            stage16(SC, ar);
            WFENCE();
            float T[16];
            #pragma unroll
            for (int j = 0; j < 16; ++j) T[j] = 0.f;
            #pragma unroll 2
            for (int k = 0; k < 30; ++k)          // T = Xih * A (orig coords)
                fma16(SC, k, XI[(k << 5) + il], T);
            WFENCE();
            stage16(SC, T);                        // A dead (in-order WAR safe)
            WFENCE();
            float md[16];
            #pragma unroll
            for (int j = 0; j < 16; ++j) md[j] = 0.f;
            #pragma unroll 2
            for (int k = 0; k < 30; ++k)          // mid = T * Xih (orig coords)
                fma16(XI, k, SC[(k << 5) + il], md);
            WFENCE();
            stage16(SC, md);
            WFENCE();
            float a2[16], v2[16];
            xload16(SC, a2);
            jacobi(a2, v2);
            if (wlane < 32) FDA[il] = logf(fmaxf(a2[0], 1e-8f));
            WFENCE();
            stage16(SC, v2);
            WFENCE();
            const float wo = WS[o];
            #pragma unroll 2
            for (int k = 0; k < 32; ++k)          // Lacc += wo * V log(L) V^T (all slots)
                fma16(SC, k, wo * FDA[k] * SC[(k << 5) + il], Lacc);
        }

        // ---- E = expm(L); X' = Xh E Xh ----
        WFENCE();
        stage16(SC, Lacc);
        WFENCE();
        float a3[16], v3[16];
        xload16(SC, a3);
        jacobi(a3, v3);
        if (wlane < 32) FDA[il] = expf(fmaxf(a3[0], 1e-8f));   // ref clamps before exp
        WFENCE();
        stage16(SC, v3);
        WFENCE();
        float E[16];
        #pragma unroll
        for (int j = 0; j < 16; ++j) E[j] = 0.f;
        #pragma unroll 2
        for (int k = 0; k < 32; ++k)              // E = V exp(L) V^T (all slots)
            fma16(SC, k, FDA[k] * SC[(k << 5) + il], E);
        // un-park Xh row slice (order the global store->load round-trip)
        float xr[16];
        #pragma unroll
        for (int j = 0; j < 16; ++j) xr[j] = 0.f;
        VSYNC();
        if (rr) loadA(orow, xr);
        WFENCE();
        stage16(XI, E);        // XI = E (Xih dead)
        stage16(SC, xr);       // SC = Xh (v3 dead; in-order safe)
        WFENCE();
        float T2[16];
        #pragma unroll
        for (int j = 0; j < 16; ++j) T2[j] = 0.f;
        #pragma unroll 2
        for (int k = 0; k < 30; ++k)              // T2 = Xh * E (orig coords)
            fma16(XI, k, SC[(k << 5) + il], T2);
        WFENCE();
        stage16(XI, T2);       // E dead
        WFENCE();
        #pragma unroll
        for (int j = 0; j < 16; ++j) X[j] = 0.f;
        #pragma unroll 2
        for (int k = 0; k < 30; ++k)              // X' = T2 * Xh (orig coords)
            fma16(SC, k, XI[(k << 5) + il], X);
    }

    if (rr) {
        #pragma unroll
        for (int u = 0; u < 7; ++u)
            *(float2*)(orow + 2 * u) = make_float2(X[2*u], X[2*u+1]);
        if (cbit == 0)
            *(float2*)(orow + 14) = make_float2(X[14], X[15]);
    }
}

extern "C" void kernel_launch(void* const* d_in, const int* in_sizes, int n_in,
                              void* d_out, int out_size, void* d_ws, size_t ws_size,
                              hipStream_t stream) {
    const float* spds   = (const float*)d_in[0];
    const float* alphas = (const float*)d_in[1];
    float* out = (float*)d_out;
    const int Mtot = in_sizes[0] / (NOPS * 900);   // 8192
    karcher_kernel<<<dim3((Mtot + WPB - 1) / WPB), dim3(64 * WPB), 0, stream>>>(
        spds, alphas, out, Mtot);
}